// Round 3
// baseline (7159.695 us; speedup 1.0000x reference)
//
#include <hip/hip_runtime.h>
#include <stdint.h>

#define B_ 64
#define T_ 512
#define D_ 1024
#define U_ 1024
#define G4_ 4096
#define M_ (B_ * T_)  // 32768

typedef unsigned short u16;
typedef float f32x4 __attribute__((ext_vector_type(4)));
typedef _Float16 f16x8 __attribute__((ext_vector_type(8)));
typedef unsigned short u16x4 __attribute__((ext_vector_type(4)));

__device__ __forceinline__ u16 f2h(float f) {
  union { _Float16 h; u16 u; } v; v.h = (_Float16)f; return v.u;
}
__device__ __forceinline__ float h2f(u16 u) {
  union { _Float16 h; u16 u; } v; v.u = u; return (float)v.h;
}
__device__ __forceinline__ float sigm(float x) { return 1.f / (1.f + __expf(-x)); }
__device__ __forceinline__ float tanhf_(float x) {
  x = fminf(12.f, fmaxf(-12.f, x));
  float e = __expf(2.f * x);
  return (e - 1.f) / (e + 1.f);
}

__device__ __forceinline__ void glds16(const void* g, void* l) {
  __builtin_amdgcn_global_load_lds(
      (const __attribute__((address_space(1))) uint32_t*)g,
      (__attribute__((address_space(3))) uint32_t*)l, 16, 0, 0);
}

// Stage R rows x 128 bytes from global (row stride gs bytes) into a linear LDS
// tile. LDS dest is linear (glds requirement); the XOR swizzle (row&7)<<4 is
// applied to the GLOBAL source offset (rule #21: pre-swizzled source), and the
// same XOR is applied on read in read_frag.
template <int R>
__device__ __forceinline__ void stage_tile(const char* gbase, long gs, char* lds, int tid) {
  const int lane = tid & 63, wid = tid >> 6;
#pragma unroll
  for (int j = wid; j < R / 8; j += 4) {  // each wave-instr covers 1KB = 8 rows
    const int row = j * 8 + (lane >> 3);
    const int lg = ((lane & 7) * 16) ^ ((row & 7) << 4);
    glds16(gbase + (long)row * gs + lg, lds + j * 1024);
  }
}

// A-frag: row = m (lane&15), k = (lane>>4)*8 + j  (k-contiguous 16B)
// B-frag from transposed W [n][k]: row = n (lane&15), same k layout.
__device__ __forceinline__ f16x8 read_frag(const char* lds, int row, int kbyte) {
  const int ph = row * 128 + (kbyte ^ ((row & 7) << 4));
  return *(const f16x8*)(lds + ph);
}

#define MFMA_(a, b, c) __builtin_amdgcn_mfma_f32_16x16x32_f16(a, b, c, 0, 0, 0)

// ---------------- prep kernels ----------------

__global__ __launch_bounds__(256) void cast_x_kernel(const float* __restrict__ x,
                                                     u16* __restrict__ xb) {
  const long n = (long)M_ * D_ / 4;
  for (long i = (long)blockIdx.x * blockDim.x + threadIdx.x; i < n;
       i += (long)gridDim.x * blockDim.x) {
    f32x4 v = ((const f32x4*)x)[i];
    u16x4 r;
#pragma unroll
    for (int j = 0; j < 4; ++j) r[j] = f2h(v[j]);
    ((u16x4*)xb)[i] = r;
  }
}

// Packed column p = ub*64 + g*16 + ui  <->  original col = g*1024 + ub*16 + ui.
// Output layout: wT[d][p][k] (transposed, k-contiguous), fp16.
__global__ __launch_bounds__(256) void pack_w_kernel(const float* __restrict__ Wf,
                                                     const float* __restrict__ Wb,
                                                     u16* __restrict__ wxT,
                                                     u16* __restrict__ whT) {
  const int idx = blockIdx.x * 256 + threadIdx.x;  // grid covers 2*2*4096*64
  const int p = idx & 4095;
  const int kc = (idx >> 12) & 63;
  const int part = (idx >> 18) & 1;  // 0 = x rows [0,1024), 1 = h rows [1024,2048)
  const int d = (idx >> 19) & 1;
  const float* W = d ? Wb : Wf;
  const int orig = ((p >> 4) & 3) * 1024 + ((p >> 6) << 4) + (p & 15);
  u16* dst = (part ? whT : wxT) + ((long)d * G4_ + p) * 1024 + kc * 16;
  const float* src = W + ((long)(part * 1024 + kc * 16)) * G4_ + orig;
#pragma unroll
  for (int j = 0; j < 16; ++j) dst[j] = f2h(src[(long)j * G4_]);
}

// ---------------- big x-projection GEMM ----------------
// xproj[d][b][t][p] (fp16) = x[b][t][:] @ Wx_d[:, orig(p)] + bias_d[orig(p)]
// BM=64, BN=128, BK=64; 4 waves (2x2), wave tile 32x64.
__global__ __launch_bounds__(256) void gemm_xproj(const u16* __restrict__ xbf,
                                                  const u16* __restrict__ wT,
                                                  const float* __restrict__ bF,
                                                  const float* __restrict__ bB,
                                                  u16* __restrict__ xproj) {
  __shared__ __align__(16) char smem[48 * 1024];
  const int tid = threadIdx.x, lane = tid & 63, wid = tid >> 6;
  const int wr = wid >> 1, wc = wid & 1;
  const int tm = blockIdx.x * 64, tn = blockIdx.y * 128, d = blockIdx.z;
  const char* Ag = (const char*)xbf + (long)tm * (D_ * 2);
  const char* Bg = (const char*)(wT + ((long)d * G4_ + tn) * 1024);

  f32x4 acc[2][4];
#pragma unroll
  for (int mi = 0; mi < 2; ++mi)
#pragma unroll
    for (int ni = 0; ni < 4; ++ni)
#pragma unroll
      for (int v = 0; v < 4; ++v) acc[mi][ni][v] = 0.f;

  stage_tile<64>(Ag, D_ * 2, smem, tid);
  stage_tile<128>(Bg, 1024 * 2, smem + 16384, tid);
  __syncthreads();
  const int rA = lane & 15, kb = (lane >> 4) * 16;

  for (int cc = 0; cc < 16; ++cc) {
    const int cur = cc & 1;
    char* Ac = smem + cur * 8192;
    char* Bc = smem + 16384 + cur * 16384;
    if (cc + 1 < 16) {
      stage_tile<64>(Ag + (cc + 1) * 128, D_ * 2, smem + (cur ^ 1) * 8192, tid);
      stage_tile<128>(Bg + (cc + 1) * 128, 1024 * 2, smem + 16384 + (cur ^ 1) * 16384, tid);
    }
    f16x8 aF[2][2], bFr[4][2];
#pragma unroll
    for (int mi = 0; mi < 2; ++mi)
#pragma unroll
      for (int ks = 0; ks < 2; ++ks)
        aF[mi][ks] = read_frag(Ac, wr * 32 + mi * 16 + rA, kb + ks * 64);
#pragma unroll
    for (int ni = 0; ni < 4; ++ni)
#pragma unroll
      for (int ks = 0; ks < 2; ++ks)
        bFr[ni][ks] = read_frag(Bc, wc * 64 + ni * 16 + rA, kb + ks * 64);
#pragma unroll
    for (int mi = 0; mi < 2; ++mi)
#pragma unroll
      for (int ni = 0; ni < 4; ++ni)
#pragma unroll
        for (int ks = 0; ks < 2; ++ks)
          acc[mi][ni] = MFMA_(aF[mi][ks], bFr[ni][ks], acc[mi][ni]);
    __syncthreads();
  }

  const float* bias = d ? bB : bF;
#pragma unroll
  for (int ni = 0; ni < 4; ++ni) {
    const int p = tn + wc * 64 + ni * 16 + rA;
    const int orig = ((p >> 4) & 3) * 1024 + ((p >> 6) << 4) + (p & 15);
    const float bv = bias[orig];
#pragma unroll
    for (int mi = 0; mi < 2; ++mi) {
      const int m0 = tm + wr * 32 + mi * 16 + (lane >> 4) * 4;
#pragma unroll
      for (int v = 0; v < 4; ++v) {
        const int m = m0 + v, b = m >> 9, t = m & 511;
        xproj[(((long)d * B_ + b) * T_ + t) * G4_ + p] = f2h(acc[mi][ni][v] + bv);
      }
    }
  }
}

// ---------------- per-timestep recurrent kernel ----------------
// grid: (64 unit-blocks, 2 dirs), 256 threads. Block output: 64 batch x 64
// packed cols (= 16 units x 4 gates). FUSED=1 additionally folds x_t@Wx
// (K = 2048 total) when xproj doesn't fit in workspace.
template <int FUSED>
__global__ __launch_bounds__(256) void lstm_step(
    const u16* __restrict__ whT, const u16* __restrict__ wxT,
    const u16* __restrict__ xbf, const u16* __restrict__ xproj,
    const float* __restrict__ bF, const float* __restrict__ bB,
    const u16* __restrict__ h_read, u16* __restrict__ h_write,
    float* __restrict__ c_state, float* __restrict__ out, int s) {
  __shared__ __align__(16) char smem[32 * 1024];
  float* zbuf = (float*)smem;  // aliases A tiles; used after final barrier
  const int tid = threadIdx.x, lane = tid & 63, wid = tid >> 6;
  const int wr = wid >> 1, wc = wid & 1;
  const int ub = blockIdx.x, d = blockIdx.y;
  const int t = d ? (T_ - 1 - s) : s;
  const char* hA = (const char*)(h_read + (long)d * B_ * U_);
  const char* Bh = (const char*)(whT + ((long)d * G4_ + ub * 64) * 1024);
  const char* xA = (const char*)xbf + (long)t * (D_ * 2);
  const char* Bx = (const char*)(wxT + ((long)d * G4_ + ub * 64) * 1024);
  const int NCC = FUSED ? 32 : 16;

  auto stage = [&](int cc, int buf) {
    char* Ad = smem + buf * 8192;
    char* Bd = smem + 16384 + buf * 8192;
    if (cc < 16) {
      stage_tile<64>(hA + cc * 128, U_ * 2, Ad, tid);
      stage_tile<64>(Bh + cc * 128, 1024 * 2, Bd, tid);
    } else {
      const int cx = cc - 16;
      stage_tile<64>(xA + cx * 128, (long)T_ * D_ * 2, Ad, tid);
      stage_tile<64>(Bx + cx * 128, 1024 * 2, Bd, tid);
    }
  };

  f32x4 acc[2][2];
#pragma unroll
  for (int mi = 0; mi < 2; ++mi)
#pragma unroll
    for (int ni = 0; ni < 2; ++ni)
#pragma unroll
      for (int v = 0; v < 4; ++v) acc[mi][ni][v] = 0.f;

  stage(0, 0);
  __syncthreads();
  const int rA = lane & 15, kb = (lane >> 4) * 16;

  for (int cc = 0; cc < NCC; ++cc) {
    const int cur = cc & 1;
    char* Ac = smem + cur * 8192;
    char* Bc = smem + 16384 + cur * 8192;
    if (cc + 1 < NCC) stage(cc + 1, cur ^ 1);
    f16x8 aF[2][2], bFr[2][2];
#pragma unroll
    for (int mi = 0; mi < 2; ++mi)
#pragma unroll
      for (int ks = 0; ks < 2; ++ks)
        aF[mi][ks] = read_frag(Ac, wr * 32 + mi * 16 + rA, kb + ks * 64);
#pragma unroll
    for (int ni = 0; ni < 2; ++ni)
#pragma unroll
      for (int ks = 0; ks < 2; ++ks)
        bFr[ni][ks] = read_frag(Bc, wc * 32 + ni * 16 + rA, kb + ks * 64);
#pragma unroll
    for (int mi = 0; mi < 2; ++mi)
#pragma unroll
      for (int ni = 0; ni < 2; ++ni)
#pragma unroll
        for (int ks = 0; ks < 2; ++ks)
          acc[mi][ni] = MFMA_(aF[mi][ks], bFr[ni][ks], acc[mi][ni]);
    __syncthreads();
  }

  // z -> LDS (f32), then gate math
#pragma unroll
  for (int mi = 0; mi < 2; ++mi)
#pragma unroll
    for (int ni = 0; ni < 2; ++ni)
#pragma unroll
      for (int v = 0; v < 4; ++v) {
        const int row = wr * 32 + mi * 16 + (lane >> 4) * 4 + v;
        const int col = wc * 32 + ni * 16 + rA;
        zbuf[row * 64 + col] = acc[mi][ni][v];
      }
  __syncthreads();

  const int b = tid >> 2, u0 = (tid & 3) * 4;
  const float* bias = d ? bB : bF;
#pragma unroll
  for (int j = 0; j < 4; ++j) {
    const int ui = u0 + j, u = ub * 16 + ui;
    float zi = zbuf[b * 64 + ui];
    float zf = zbuf[b * 64 + 16 + ui];
    float zo = zbuf[b * 64 + 32 + ui];
    float zg = zbuf[b * 64 + 48 + ui];
    if (FUSED) {
      zi += bias[u]; zf += bias[1024 + u]; zo += bias[2048 + u]; zg += bias[3072 + u];
    } else {
      const u16* xp = xproj + (((long)d * B_ + b) * T_ + t) * G4_ + ub * 64;
      zi += h2f(xp[ui]); zf += h2f(xp[16 + ui]);
      zo += h2f(xp[32 + ui]); zg += h2f(xp[48 + ui]);
    }
    const long ci = (((long)d * B_ + b) << 10) + u;
    const float c = c_state[ci];
    const float i_ = sigm(zi), ff = sigm(zf), o_ = sigm(zo), g_ = tanhf_(zg);
    const float cn = ff * c + i_ * g_;
    const float hn = o_ * tanhf_(cn);
    c_state[ci] = cn;
    h_write[ci] = f2h(hn);
    out[(((long)b * T_ + t) << 11) + ((long)d << 10) + u] = hn;
  }
}

// ---------------- host launch ----------------

extern "C" void kernel_launch(void* const* d_in, const int* in_sizes, int n_in,
                              void* d_out, int out_size, void* d_ws, size_t ws_size,
                              hipStream_t stream) {
  const float* x = (const float*)d_in[0];
  const float* Wf = (const float*)d_in[1];
  const float* bfp = (const float*)d_in[2];
  const float* Wb = (const float*)d_in[3];
  const float* bbp = (const float*)d_in[4];
  float* out = (float*)d_out;
  char* ws = (char*)d_ws;

  size_t off = 0;
  auto alloc = [&](size_t bytes) {
    char* p = ws + off;
    off = (off + bytes + 255) & ~(size_t)255;
    return p;
  };
  u16* xbf = (u16*)alloc((size_t)M_ * D_ * 2);            // 64 MB
  u16* wxT = (u16*)alloc((size_t)2 * G4_ * 1024 * 2);     // 16 MB
  u16* whT = (u16*)alloc((size_t)2 * G4_ * 1024 * 2);     // 16 MB
  u16* hst = (u16*)alloc((size_t)2 * 2 * B_ * U_ * 2);    // ping-pong h, [par][d][b][u]
  float* cst = (float*)alloc((size_t)2 * B_ * U_ * 4);    // cell state f32
  const size_t base_need = off;
  const size_t xproj_bytes = (size_t)2 * B_ * T_ * G4_ * 2;  // 512 MB
  const bool fused = (ws_size < base_need + xproj_bytes + 256);
  u16* xproj = fused ? nullptr : (u16*)alloc(xproj_bytes);

  hipMemsetAsync(hst, 0, (size_t)2 * 2 * B_ * U_ * 2, stream);
  hipMemsetAsync(cst, 0, (size_t)2 * B_ * U_ * 4, stream);

  cast_x_kernel<<<2048, 256, 0, stream>>>(x, xbf);
  pack_w_kernel<<<4096, 256, 0, stream>>>(Wf, Wb, wxT, whT);

  if (!fused) {
    dim3 gg(M_ / 64, G4_ / 128, 2);
    gemm_xproj<<<gg, 256, 0, stream>>>(xbf, wxT, bfp, bbp, xproj);
  }

  for (int s = 0; s < T_; ++s) {
    const u16* hr = hst + (size_t)(s & 1) * 2 * B_ * U_;
    u16* hw = hst + (size_t)((s + 1) & 1) * 2 * B_ * U_;
    dim3 gs_(U_ / 16, 2);
    if (fused)
      lstm_step<1><<<gs_, 256, 0, stream>>>(whT, wxT, xbf, nullptr, bfp, bbp,
                                            hr, hw, cst, out, s);
    else
      lstm_step<0><<<gs_, 256, 0, stream>>>(whT, nullptr, nullptr, xproj, bfp, bbp,
                                            hr, hw, cst, out, s);
  }
}

// Round 4
// 4164.477 us; speedup vs baseline: 1.7192x; 1.7192x over previous
//
#include <hip/hip_runtime.h>
#include <stdint.h>

#define B_ 64
#define T_ 512
#define D_ 1024
#define U_ 1024
#define G4_ 4096
#define M_ (B_ * T_)  // 32768

typedef unsigned short u16;
typedef float f32x4 __attribute__((ext_vector_type(4)));
typedef _Float16 f16x8 __attribute__((ext_vector_type(8)));
typedef unsigned short u16x4 __attribute__((ext_vector_type(4)));

__device__ __forceinline__ u16 f2h(float f) {
  union { _Float16 h; u16 u; } v; v.h = (_Float16)f; return v.u;
}
__device__ __forceinline__ float h2f(u16 u) {
  union { _Float16 h; u16 u; } v; v.u = u; return (float)v.h;
}
__device__ __forceinline__ float sigm(float x) { return 1.f / (1.f + __expf(-x)); }
__device__ __forceinline__ float tanhf_(float x) {
  x = fminf(12.f, fmaxf(-12.f, x));
  float e = __expf(2.f * x);
  return (e - 1.f) / (e + 1.f);
}

__device__ __forceinline__ void glds16(const void* g, void* l) {
  __builtin_amdgcn_global_load_lds(
      (const __attribute__((address_space(1))) uint32_t*)g,
      (__attribute__((address_space(3))) uint32_t*)l, 16, 0, 0);
}

// ---- generic row-strided stager (GEMM + fused fallback): swizzle (row&7)<<4
// applied to GLOBAL source (rule #21), LDS linear; read_frag applies same XOR.
template <int R>
__device__ __forceinline__ void stage_tile(const char* gbase, long gs, char* lds, int tid) {
  const int lane = tid & 63, wid = tid >> 6;
#pragma unroll
  for (int j = wid; j < R / 8; j += 4) {  // each wave-instr covers 1KB = 8 rows
    const int row = j * 8 + (lane >> 3);
    const int lg = ((lane & 7) * 16) ^ ((row & 7) << 4);
    glds16(gbase + (long)row * gs + lg, lds + j * 1024);
  }
}

__device__ __forceinline__ f16x8 read_frag(const char* lds, int row, int kbyte) {
  const int ph = row * 128 + (kbyte ^ ((row & 7) << 4));
  return *(const f16x8*)(lds + ph);
}

#define MFMA_(a, b, c) __builtin_amdgcn_mfma_f32_16x16x32_f16(a, b, c, 0, 0, 0)

// ---------------- prep kernels ----------------

__global__ __launch_bounds__(256) void cast_x_kernel(const float* __restrict__ x,
                                                     u16* __restrict__ xb) {
  const long n = (long)M_ * D_ / 4;
  for (long i = (long)blockIdx.x * blockDim.x + threadIdx.x; i < n;
       i += (long)gridDim.x * blockDim.x) {
    f32x4 v = ((const f32x4*)x)[i];
    u16x4 r;
#pragma unroll
    for (int j = 0; j < 4; ++j) r[j] = f2h(v[j]);
    ((u16x4*)xb)[i] = r;
  }
}

// Packed column p = ub*64 + g*16 + ui  <->  original col = g*1024 + ub*16 + ui.
__global__ __launch_bounds__(256) void pack_w_kernel(const float* __restrict__ Wf,
                                                     const float* __restrict__ Wb,
                                                     u16* __restrict__ wxT,
                                                     u16* __restrict__ whT) {
  const int idx = blockIdx.x * 256 + threadIdx.x;
  const int p = idx & 4095;
  const int kc = (idx >> 12) & 63;
  const int part = (idx >> 18) & 1;
  const int d = (idx >> 19) & 1;
  const float* W = d ? Wb : Wf;
  const int orig = ((p >> 4) & 3) * 1024 + ((p >> 6) << 4) + (p & 15);
  u16* dst = (part ? whT : wxT) + ((long)d * G4_ + p) * 1024 + kc * 16;
  const float* src = W + ((long)(part * 1024 + kc * 16)) * G4_ + orig;
#pragma unroll
  for (int j = 0; j < 16; ++j) dst[j] = f2h(src[(long)j * G4_]);
}

// ---------------- big x-projection GEMM (128x128 tile) ----------------
// Writes xp2 layout [d][t][ub(64)][bh(2)][32][64] fp16, bias folded in.
__global__ __launch_bounds__(256) void gemm_xproj2(const u16* __restrict__ xbf,
                                                   const u16* __restrict__ wT,
                                                   const float* __restrict__ bF,
                                                   const float* __restrict__ bB,
                                                   u16* __restrict__ xp2) {
  __shared__ __align__(16) char smem[64 * 1024];
  const int tid = threadIdx.x, lane = tid & 63, wid = tid >> 6;
  const int wr = wid >> 1, wc = wid & 1;
  const int tm = blockIdx.x * 128, tn = blockIdx.y * 128, d = blockIdx.z;
  const char* Ag = (const char*)xbf + (long)tm * 2048;
  const char* Bg = (const char*)wT + ((long)d * G4_ + tn) * 2048;

  f32x4 acc[4][4];
#pragma unroll
  for (int mi = 0; mi < 4; ++mi)
#pragma unroll
    for (int ni = 0; ni < 4; ++ni)
#pragma unroll
      for (int v = 0; v < 4; ++v) acc[mi][ni][v] = 0.f;

  stage_tile<128>(Ag, 2048, smem, tid);
  stage_tile<128>(Bg, 2048, smem + 32768, tid);
  __syncthreads();
  const int rA = lane & 15, kb = (lane >> 4) * 16;

  for (int cc = 0; cc < 16; ++cc) {
    const int cur = cc & 1;
    char* Ac = smem + cur * 16384;
    char* Bc = smem + 32768 + cur * 16384;
    if (cc + 1 < 16) {
      stage_tile<128>(Ag + (cc + 1) * 128, 2048, smem + (cur ^ 1) * 16384, tid);
      stage_tile<128>(Bg + (cc + 1) * 128, 2048, smem + 32768 + (cur ^ 1) * 16384, tid);
    }
    f16x8 aF[4][2], bFr[4][2];
#pragma unroll
    for (int mi = 0; mi < 4; ++mi)
#pragma unroll
      for (int ks = 0; ks < 2; ++ks)
        aF[mi][ks] = read_frag(Ac, wr * 64 + mi * 16 + rA, kb + ks * 64);
#pragma unroll
    for (int ni = 0; ni < 4; ++ni)
#pragma unroll
      for (int ks = 0; ks < 2; ++ks)
        bFr[ni][ks] = read_frag(Bc, wc * 64 + ni * 16 + rA, kb + ks * 64);
#pragma unroll
    for (int mi = 0; mi < 4; ++mi)
#pragma unroll
      for (int ni = 0; ni < 4; ++ni)
#pragma unroll
        for (int ks = 0; ks < 2; ++ks)
          acc[mi][ni] = MFMA_(aF[mi][ks], bFr[ni][ks], acc[mi][ni]);
    __syncthreads();
  }

  const float* bias = d ? bB : bF;
#pragma unroll
  for (int ni = 0; ni < 4; ++ni) {
    const int p = tn + wc * 64 + ni * 16 + rA;
    const int orig = ((p >> 4) & 3) * 1024 + ((p >> 6) << 4) + (p & 15);
    const float bv = bias[orig];
    const int ub2 = p >> 6, pl = p & 63;
#pragma unroll
    for (int mi = 0; mi < 4; ++mi) {
      const int m0 = tm + wr * 64 + mi * 16 + (lane >> 4) * 4;
#pragma unroll
      for (int v = 0; v < 4; ++v) {
        const int m = m0 + v, b = m >> 9, t = m & 511;
        const int bh = b >> 5, br = b & 31;
        xp2[(((((long)d * T_ + t) * 64 + ub2) * 2 + bh) * 32 + br) * 64 + pl] =
            f2h(acc[mi][ni][v] + bv);
      }
    }
  }
}

// ---------------- streamlined per-timestep kernel ----------------
// grid (128, 2): g = blockIdx.x -> ub = g>>1, d = g&1; bh = blockIdx.y.
// Block: 32 batch x 64 packed cols (16 units), K=1024.
// LDS: A(h) 64KB resident; Wh ring 4 x 16KB (8 chunks of K=128);
// xp 4KB; zbuf 8KB. Counted-vmcnt pipeline, raw barriers (no vmcnt(0) drain).

__device__ __forceinline__ void stage_hA(const char* g, char* lds, int tid) {
  const int lane = tid & 63, wid = tid >> 6;
#pragma unroll
  for (int q = 0; q < 16; ++q) {
    const int idx = wid + q * 4;            // 64 instrs, 64KB contiguous
    const int row = idx * 8 + (lane >> 3);  // row128 in [0,512)
    const int off = ((lane & 7) * 16) ^ (((row >> 4) & 7) << 4);  // swz by b-row
    glds16(g + (long)row * 128 + off, lds + idx * 1024);
  }
}

__device__ __forceinline__ void stage_Bchunk(const char* wbase, int cc, char* slot, int tid) {
  const int lane = tid & 63, wid = tid >> 6;
#pragma unroll
  for (int q = 0; q < 4; ++q) {
    const int idx = wid + q * 4;            // 16 instrs = 16KB
    const int row = idx * 8 + (lane >> 3);  // [0,128): pi = row>>1, kc2 = row&1
    const int off = ((lane & 7) * 16) ^ (((row >> 1) & 7) << 4);  // swz by p-row
    glds16(wbase + (long)(row >> 1) * 2048 + cc * 256 + (row & 1) * 128 + off,
           slot + idx * 1024);
  }
}

__device__ __forceinline__ void stage_xpb(const char* g, char* lds, int tid) {
  const int lane = tid & 63, wid = tid >> 6;
  glds16(g + wid * 1024 + lane * 16 - lane * 16 + (long)lane * 16, lds + wid * 1024);
}

template <int CC>
__device__ __forceinline__ void kstep(char* smem, const char* wbase, int tid,
                                      int wr, int wc, int rA, int kq,
                                      f32x4 (&acc)[2]) {
  constexpr int REM = 7 - CC;
  constexpr int N = 4 * (REM < 3 ? REM : 3);
  asm volatile("s_waitcnt vmcnt(%0)" :: "i"(N) : "memory");
  __builtin_amdgcn_s_barrier();
  asm volatile("" ::: "memory");
  const char* A = smem;
  const char* Bslot = smem + 65536 + (CC & 3) * 16384;
  f16x8 aF[4], bF[2][4];
  const int br = wr * 16 + rA;
#pragma unroll
  for (int ks = 0; ks < 4; ++ks) {
    const int kbyte = CC * 256 + ks * 64 + kq * 16;
    aF[ks] = *(const f16x8*)(A + br * 2048 + (kbyte ^ ((br & 7) << 4)));
  }
#pragma unroll
  for (int ni = 0; ni < 2; ++ni) {
    const int pi = wc * 32 + ni * 16 + rA;
#pragma unroll
    for (int ks = 0; ks < 4; ++ks) {
      const int kb2 = ks * 64 + kq * 16;
      bF[ni][ks] = *(const f16x8*)(Bslot + pi * 256 + (kb2 ^ ((pi & 7) << 4)));
    }
  }
#pragma unroll
  for (int ni = 0; ni < 2; ++ni)
#pragma unroll
    for (int ks = 0; ks < 4; ++ks)
      acc[ni] = MFMA_(aF[ks], bF[ni][ks], acc[ni]);
  asm volatile("s_waitcnt lgkmcnt(0)" ::: "memory");
  __builtin_amdgcn_sched_barrier(0);
  __builtin_amdgcn_s_barrier();
  asm volatile("" ::: "memory");
  if (CC + 4 < 8)
    stage_Bchunk(wbase, CC + 4, smem + 65536 + ((CC + 4) & 3) * 16384, tid);
}

__global__ __launch_bounds__(256) void lstm_step2(
    const u16* __restrict__ whT, const u16* __restrict__ xp2,
    const u16* __restrict__ h_read, u16* __restrict__ h_write,
    float* __restrict__ c_state, float* __restrict__ out, int s) {
  __shared__ __align__(16) char smem[143360];  // A 64K | ring 64K | xp 4K | zbuf 8K
  const int tid = threadIdx.x, lane = tid & 63, wid = tid >> 6;
  const int wr = wid >> 1, wc = wid & 1, rA = lane & 15, kq = lane >> 4;
  const int g = blockIdx.x, ub = g >> 1, d = g & 1, bh = blockIdx.y;
  const int t = d ? (T_ - 1 - s) : s;
  const char* hA = (const char*)h_read + ((long)d * B_ + bh * 32) * 2048;
  const char* wbase = (const char*)whT + ((long)d * G4_ + ub * 64) * 2048;
  const char* xg = (const char*)xp2 + ((((long)d * T_ + t) * 64 + ub) * 2 + bh) * 4096;
  char* xpb = smem + 131072;
  float* zbuf = (float*)(smem + 135168);

  // issue order matters for vmcnt counting: xp(1) + A(16) + B0..B3(16) = 33/wave
  stage_xpb(xg, xpb, tid);
  stage_hA(hA, smem, tid);
#pragma unroll
  for (int c0 = 0; c0 < 4; ++c0)
    stage_Bchunk(wbase, c0, smem + 65536 + c0 * 16384, tid);

  f32x4 acc[2];
#pragma unroll
  for (int ni = 0; ni < 2; ++ni)
#pragma unroll
    for (int v = 0; v < 4; ++v) acc[ni][v] = 0.f;

  kstep<0>(smem, wbase, tid, wr, wc, rA, kq, acc);
  kstep<1>(smem, wbase, tid, wr, wc, rA, kq, acc);
  kstep<2>(smem, wbase, tid, wr, wc, rA, kq, acc);
  kstep<3>(smem, wbase, tid, wr, wc, rA, kq, acc);
  kstep<4>(smem, wbase, tid, wr, wc, rA, kq, acc);
  kstep<5>(smem, wbase, tid, wr, wc, rA, kq, acc);
  kstep<6>(smem, wbase, tid, wr, wc, rA, kq, acc);
  kstep<7>(smem, wbase, tid, wr, wc, rA, kq, acc);

  // z -> LDS, gate exchange
#pragma unroll
  for (int ni = 0; ni < 2; ++ni)
#pragma unroll
    for (int v = 0; v < 4; ++v) {
      const int row = wr * 16 + kq * 4 + v;
      const int col = wc * 32 + ni * 16 + rA;
      zbuf[row * 64 + col] = acc[ni][v];
    }
  __syncthreads();

  const u16* xph = (const u16*)xpb;
#pragma unroll
  for (int j = 0; j < 2; ++j) {
    const int o = tid * 2 + j, bl = o >> 4, ui = o & 15;
    const float zi = zbuf[bl * 64 + ui]      + h2f(xph[bl * 64 + ui]);
    const float zf = zbuf[bl * 64 + 16 + ui] + h2f(xph[bl * 64 + 16 + ui]);
    const float zo = zbuf[bl * 64 + 32 + ui] + h2f(xph[bl * 64 + 32 + ui]);
    const float zg = zbuf[bl * 64 + 48 + ui] + h2f(xph[bl * 64 + 48 + ui]);
    const int bglob = bh * 32 + bl, u = ub * 16 + ui;
    const long ci = ((long)d * B_ + bglob) * 1024 + u;
    const float c = c_state[ci];
    const float i_ = sigm(zi), ff = sigm(zf), o_ = sigm(zo), g_ = tanhf_(zg);
    const float cn = ff * c + i_ * g_;
    const float hn = o_ * tanhf_(cn);
    c_state[ci] = cn;
    h_write[ci] = f2h(hn);
    out[((long)bglob * T_ + t) * 2048 + d * 1024 + u] = hn;
  }
}

// ---------------- fused fallback (small workspace): r3-proven structure ------
__global__ __launch_bounds__(256) void lstm_step_fused(
    const u16* __restrict__ whT, const u16* __restrict__ wxT,
    const u16* __restrict__ xbf,
    const float* __restrict__ bF, const float* __restrict__ bB,
    const u16* __restrict__ h_read, u16* __restrict__ h_write,
    float* __restrict__ c_state, float* __restrict__ out, int s) {
  __shared__ __align__(16) char smem[32 * 1024];
  float* zbuf = (float*)smem;
  const int tid = threadIdx.x, lane = tid & 63, wid = tid >> 6;
  const int wr = wid >> 1, wc = wid & 1;
  const int ub = blockIdx.x, d = blockIdx.y;
  const int t = d ? (T_ - 1 - s) : s;
  const char* hA = (const char*)(h_read + (long)d * B_ * U_);
  const char* Bh = (const char*)(whT + ((long)d * G4_ + ub * 64) * 1024);
  const char* xA = (const char*)xbf + (long)t * (D_ * 2);
  const char* Bx = (const char*)(wxT + ((long)d * G4_ + ub * 64) * 1024);

  auto stage = [&](int cc, int buf) {
    char* Ad = smem + buf * 8192;
    char* Bd = smem + 16384 + buf * 8192;
    if (cc < 16) {
      stage_tile<64>(hA + cc * 128, U_ * 2, Ad, tid);
      stage_tile<64>(Bh + cc * 128, 1024 * 2, Bd, tid);
    } else {
      const int cx = cc - 16;
      stage_tile<64>(xA + cx * 128, (long)T_ * D_ * 2, Ad, tid);
      stage_tile<64>(Bx + cx * 128, 1024 * 2, Bd, tid);
    }
  };

  f32x4 acc[2][2];
#pragma unroll
  for (int mi = 0; mi < 2; ++mi)
#pragma unroll
    for (int ni = 0; ni < 2; ++ni)
#pragma unroll
      for (int v = 0; v < 4; ++v) acc[mi][ni][v] = 0.f;

  stage(0, 0);
  __syncthreads();
  const int rA = lane & 15, kb = (lane >> 4) * 16;

  for (int cc = 0; cc < 32; ++cc) {
    const int cur = cc & 1;
    char* Ac = smem + cur * 8192;
    char* Bc = smem + 16384 + cur * 8192;
    if (cc + 1 < 32) stage(cc + 1, cur ^ 1);
    f16x8 aF[2][2], bFr[2][2];
#pragma unroll
    for (int mi = 0; mi < 2; ++mi)
#pragma unroll
      for (int ks = 0; ks < 2; ++ks)
        aF[mi][ks] = read_frag(Ac, wr * 32 + mi * 16 + rA, kb + ks * 64);
#pragma unroll
    for (int ni = 0; ni < 2; ++ni)
#pragma unroll
      for (int ks = 0; ks < 2; ++ks)
        bFr[ni][ks] = read_frag(Bc, wc * 32 + ni * 16 + rA, kb + ks * 64);
#pragma unroll
    for (int mi = 0; mi < 2; ++mi)
#pragma unroll
      for (int ni = 0; ni < 2; ++ni)
#pragma unroll
        for (int ks = 0; ks < 2; ++ks)
          acc[mi][ni] = MFMA_(aF[mi][ks], bFr[ni][ks], acc[mi][ni]);
    __syncthreads();
  }

#pragma unroll
  for (int mi = 0; mi < 2; ++mi)
#pragma unroll
    for (int ni = 0; ni < 2; ++ni)
#pragma unroll
      for (int v = 0; v < 4; ++v) {
        const int row = wr * 32 + mi * 16 + (lane >> 4) * 4 + v;
        const int col = wc * 32 + ni * 16 + rA;
        zbuf[row * 64 + col] = acc[mi][ni][v];
      }
  __syncthreads();

  const int b = tid >> 2, u0 = (tid & 3) * 4;
  const float* bias = d ? bB : bF;
#pragma unroll
  for (int j = 0; j < 4; ++j) {
    const int ui = u0 + j, u = ub * 16 + ui;
    float zi = zbuf[b * 64 + ui] + bias[u];
    float zf = zbuf[b * 64 + 16 + ui] + bias[1024 + u];
    float zo = zbuf[b * 64 + 32 + ui] + bias[2048 + u];
    float zg = zbuf[b * 64 + 48 + ui] + bias[3072 + u];
    const long ci = (((long)d * B_ + b) << 10) + u;
    const float c = c_state[ci];
    const float i_ = sigm(zi), ff = sigm(zf), o_ = sigm(zo), g_ = tanhf_(zg);
    const float cn = ff * c + i_ * g_;
    const float hn = o_ * tanhf_(cn);
    c_state[ci] = cn;
    h_write[ci] = f2h(hn);
    out[(((long)b * T_ + t) << 11) + ((long)d << 10) + u] = hn;
  }
}

// ---------------- host launch ----------------

extern "C" void kernel_launch(void* const* d_in, const int* in_sizes, int n_in,
                              void* d_out, int out_size, void* d_ws, size_t ws_size,
                              hipStream_t stream) {
  const float* x = (const float*)d_in[0];
  const float* Wf = (const float*)d_in[1];
  const float* bfp = (const float*)d_in[2];
  const float* Wb = (const float*)d_in[3];
  const float* bbp = (const float*)d_in[4];
  float* out = (float*)d_out;
  char* ws = (char*)d_ws;

  size_t off = 0;
  auto alloc = [&](size_t bytes) {
    char* p = ws + off;
    off = (off + bytes + 255) & ~(size_t)255;
    return p;
  };
  u16* xbf = (u16*)alloc((size_t)M_ * D_ * 2);            // 64 MB
  u16* wxT = (u16*)alloc((size_t)2 * G4_ * 1024 * 2);     // 16 MB
  u16* whT = (u16*)alloc((size_t)2 * G4_ * 1024 * 2);     // 16 MB
  u16* hst = (u16*)alloc((size_t)2 * 2 * B_ * U_ * 2);    // ping-pong h
  float* cst = (float*)alloc((size_t)2 * B_ * U_ * 4);    // cell state f32
  const size_t base_need = off;
  const size_t xproj_bytes = (size_t)2 * B_ * T_ * G4_ * 2;  // 512 MB
  const bool fused = (ws_size < base_need + xproj_bytes + 256);
  u16* xproj = fused ? nullptr : (u16*)alloc(xproj_bytes);

  hipMemsetAsync(hst, 0, (size_t)2 * 2 * B_ * U_ * 2, stream);
  hipMemsetAsync(cst, 0, (size_t)2 * B_ * U_ * 4, stream);

  cast_x_kernel<<<2048, 256, 0, stream>>>(x, xbf);
  pack_w_kernel<<<4096, 256, 0, stream>>>(Wf, Wb, wxT, whT);

  if (!fused) {
    dim3 gg(M_ / 128, G4_ / 128, 2);
    gemm_xproj2<<<gg, 256, 0, stream>>>(xbf, wxT, bfp, bbp, xproj);
    for (int s = 0; s < T_; ++s) {
      const u16* hr = hst + (size_t)(s & 1) * 2 * B_ * U_;
      u16* hw = hst + (size_t)((s + 1) & 1) * 2 * B_ * U_;
      lstm_step2<<<dim3(128, 2), 256, 0, stream>>>(whT, xproj, hr, hw, cst, out, s);
    }
  } else {
    for (int s = 0; s < T_; ++s) {
      const u16* hr = hst + (size_t)(s & 1) * 2 * B_ * U_;
      u16* hw = hst + (size_t)((s + 1) & 1) * 2 * B_ * U_;
      lstm_step_fused<<<dim3(64, 2), 256, 0, stream>>>(whT, wxT, xbf, bfp, bbp,
                                                       hr, hw, cst, out, s);
    }
  }
}